// Round 9
// baseline (700.327 us; speedup 1.0000x reference)
//
#include <hip/hip_runtime.h>
#include <hip/hip_bf16.h>

typedef __attribute__((ext_vector_type(4))) float f32x4;
typedef __attribute__((ext_vector_type(8))) short bf16x8;
typedef __attribute__((ext_vector_type(8))) unsigned short us8;
typedef __attribute__((ext_vector_type(4))) unsigned short us4;

__device__ __forceinline__ float bf2f(unsigned short u) {
    union { unsigned int i; float f; } x; x.i = ((unsigned int)u) << 16; return x.f;
}
__device__ __forceinline__ unsigned short f2bf(float f) {
    union { float f; unsigned int i; } x; x.f = f;
    unsigned int i = x.i;
    return (unsigned short)((i + 0x7FFFu + ((i >> 16) & 1u)) >> 16);
}

// ---------------- build Wt[1024][256] bf16 (transposed), biases, gate vecs ----------------
__global__ void k_conv_w(const float* __restrict__ Wq, const float* __restrict__ Wk,
                         const float* __restrict__ Wv, const float* __restrict__ Ws,
                         const float* __restrict__ bq, const float* __restrict__ bk,
                         const float* __restrict__ bv, const float* __restrict__ bs,
                         const float* __restrict__ Wg,
                         unsigned short* __restrict__ Wt, float* __restrict__ ball,
                         float* __restrict__ wga, float* __restrict__ wgb)
{
    int gid = blockIdx.x * 256 + threadIdx.x;  // 65536 threads
    int k = gid >> 8, colq = gid & 255;
    int col0 = colq * 4;
    const float* Wsel[4] = {Wq, Wk, Wv, Ws};
    const float* W = Wsel[col0 >> 8];
    int c0 = col0 & 255;
    f32x4 w = *(const f32x4*)(W + k * 256 + c0);
    for (int j = 0; j < 4; ++j)
        Wt[(size_t)(col0 + j) * 256 + k] = f2bf(w[j]);
    if (gid < 1024) {
        const float* bsel[4] = {bq, bk, bv, bs};
        ball[gid] = bsel[gid >> 8][gid & 255];
    } else if (gid < 1280) {
        int i = gid - 1024;
        wga[i] = Wg[i] + Wg[512 + i];          // coeff on skip
    } else if (gid < 1536) {
        int i = gid - 1280;
        wgb[i] = Wg[256 + i] - Wg[512 + i];    // coeff on rst
    }
}

// ---------------- fused QKV+skip GEMM: feat fp32 [M,256] x Wt [256,1024] ----------------
// outputs: qv[row][512] bf16 interleaved {q_c at 2c, v_c at 2c+1}; kb[row][256]; skipb[row][256]
#define BM 128
#define BN 128
#define BK 64
#define SST 72   // LDS row stride in bf16: 144B = 16B-aligned, bank-step 4 -> conflict-free

__global__ __launch_bounds__(256) void k_gemm(
    const float* __restrict__ A, const unsigned short* __restrict__ Bt,
    const float* __restrict__ bias, unsigned short* __restrict__ qv,
    unsigned short* __restrict__ kb, unsigned short* __restrict__ skipb, int M, int MB)
{
    __shared__ unsigned short a_sm[BM * SST];
    __shared__ unsigned short b_sm[BN * SST];
    int id = blockIdx.x;
    int rr = id & 7, bn = (id >> 3) & 7, bm = (id >> 6) * 8 + rr;  // XCD-cohort swizzle
    if (bm >= MB) return;
    int t = threadIdx.x;
    int lane = t & 63, wid = t >> 6;
    int wr = wid >> 1, wc = wid & 1;
    int l15 = lane & 15, l4 = lane >> 4;
    f32x4 acc[4][4] = {};
    for (int k0 = 0; k0 < 256; k0 += BK) {
        for (int it = 0; it < 4; ++it) {
            int c = it * 256 + t;
            int row = c >> 3;
            int ko = (c & 7) * 8;
            int grow = bm * BM + row;
            if (grow >= M) grow = M - 1;
            // A: fp32 load + convert (fused feat convert)
            const f32x4* pa = (const f32x4*)(A + (size_t)grow * 256 + k0 + ko);
            f32x4 x = pa[0], y = pa[1];
            us8 o;
            o[0] = f2bf(x[0]); o[1] = f2bf(x[1]); o[2] = f2bf(x[2]); o[3] = f2bf(x[3]);
            o[4] = f2bf(y[0]); o[5] = f2bf(y[1]); o[6] = f2bf(y[2]); o[7] = f2bf(y[3]);
            *(us8*)(a_sm + row * SST + ko) = o;
            int gcol = bn * BN + row;
            us8 vb = *(const us8*)(Bt + (size_t)gcol * 256 + k0 + ko);
            *(us8*)(b_sm + row * SST + ko) = vb;
        }
        __syncthreads();
        for (int kk = 0; kk < BK; kk += 32) {
            bf16x8 af[4], bf[4];
            for (int mi = 0; mi < 4; ++mi)
                af[mi] = *(const bf16x8*)(a_sm + (wr * 64 + mi * 16 + l15) * SST + kk + l4 * 8);
            for (int ni = 0; ni < 4; ++ni)
                bf[ni] = *(const bf16x8*)(b_sm + (wc * 64 + ni * 16 + l15) * SST + kk + l4 * 8);
            for (int mi = 0; mi < 4; ++mi)
                for (int ni = 0; ni < 4; ++ni)
                    acc[mi][ni] = __builtin_amdgcn_mfma_f32_16x16x32_bf16(af[mi], bf[ni], acc[mi][ni], 0, 0, 0);
        }
        __syncthreads();
    }
    int colb = bn * BN + wc * 64 + l15;
    for (int mi = 0; mi < 4; ++mi) {
        int rowb = bm * BM + wr * 64 + mi * 16 + l4 * 4;
        for (int ni = 0; ni < 4; ++ni) {
            int col = colb + ni * 16;
            float bv = bias[col];
            for (int r = 0; r < 4; ++r) {
                int row = rowb + r;
                if (row < M) {
                    float v = acc[mi][ni][r] + bv;
                    unsigned short h = f2bf(v);
                    if (col < 256)       qv[(size_t)row * 512 + col * 2] = h;              // q at even
                    else if (col < 512)  kb[(size_t)row * 256 + (col - 256)] = h;          // k
                    else if (col < 768)  qv[(size_t)row * 512 + (col - 512) * 2 + 1] = h;  // v at odd
                    else                 skipb[(size_t)row * 256 + (col - 768)] = h;       // skip bf16
                }
            }
        }
    }
}

// ---------------- CSR build ----------------
__global__ void k_count(const int* __restrict__ dst, int* __restrict__ cnt, int e) {
    int t = blockIdx.x * 256 + threadIdx.x;
    if (t < e) atomicAdd(&cnt[dst[t]], 1);
}
__global__ void k_scan1(const int* __restrict__ cnt, int* __restrict__ inc, int* __restrict__ bsum, int n) {
    int t = threadIdx.x;
    int i = blockIdx.x * 256 + t;
    int lane = t & 63, w = t >> 6;
    int v = (i < n) ? cnt[i] : 0;
    int s = v;
    for (int off = 1; off < 64; off <<= 1) {
        int u = __shfl_up(s, off, 64);
        if (lane >= off) s += u;
    }
    __shared__ int wt[4];
    if (lane == 63) wt[w] = s;
    __syncthreads();
    for (int j = 0; j < w; ++j) s += wt[j];
    if (i < n) inc[i] = s;
    if (t == 255) bsum[blockIdx.x] = s;
}
__global__ void k_scan2(int* __restrict__ bsum, int nb) {
    int t = threadIdx.x;
    int lane = t & 63, w = t >> 6;
    int v = (t < nb) ? bsum[t] : 0;
    int s = v;
    for (int off = 1; off < 64; off <<= 1) {
        int u = __shfl_up(s, off, 64);
        if (lane >= off) s += u;
    }
    __shared__ int wt[4];
    if (lane == 63) wt[w] = s;
    __syncthreads();
    for (int j = 0; j < w; ++j) s += wt[j];
    if (t < nb) bsum[t] = s - v;
}
__global__ void k_scan3(const int* __restrict__ cnt, int* __restrict__ rowstart, const int* __restrict__ bsum, int n, int e) {
    int i = blockIdx.x * 256 + threadIdx.x;
    if (i < n) rowstart[i] = bsum[blockIdx.x] + rowstart[i] - cnt[i];
    if (i == 0) rowstart[n] = e;
}
__global__ void k_scatter(const int* __restrict__ src, const int* __restrict__ dst,
                          const int* __restrict__ rowstart, int* __restrict__ cur,
                          int* __restrict__ esrc, int e) {
    int t = blockIdx.x * 256 + threadIdx.x;
    if (t < e) {
        int d = dst[t];
        int pos = rowstart[d] + atomicAdd(&cur[d], 1);
        esrc[pos] = src[t];
    }
}

// ---------------- fused attn + gate + LN + PReLU: one wave per dst node ----------------
__device__ __forceinline__ float red16(float sc) {
    sc += __shfl_xor(sc, 1, 16);
    sc += __shfl_xor(sc, 2, 16);
    sc += __shfl_xor(sc, 4, 16);
    sc += __shfl_xor(sc, 8, 16);
    return sc;
}
__device__ __forceinline__ float dotqv(us8 w, const float* kf) {
    return bf2f(w[0]) * kf[0] + bf2f(w[2]) * kf[1] + bf2f(w[4]) * kf[2] + bf2f(w[6]) * kf[3];
}

__global__ void k_attn(const unsigned short* __restrict__ qv,
                       const unsigned short* __restrict__ kb,
                       const unsigned short* __restrict__ skipb,
                       const int* __restrict__ rowstart, const int* __restrict__ esrc,
                       const float* __restrict__ wga, const float* __restrict__ wgb,
                       const float* __restrict__ bgp, const float* __restrict__ lns,
                       const float* __restrict__ lnb, const float* __restrict__ alphap,
                       float* __restrict__ out, int n)
{
    int node = blockIdx.x * 4 + (threadIdx.x >> 6);
    if (node >= n) return;
    int lane = threadIdx.x & 63;
    int lane4 = lane * 4;
    int lane8 = lane * 8;
    // lane l covers feature cols 4l..4l+3; head = l>>4
    us4 k4 = __builtin_nontemporal_load((const us4*)(kb + (size_t)node * 256 + lane4));
    float kf[4];
    for (int i = 0; i < 4; ++i) kf[i] = bf2f(k4[i]);
    int p0 = rowstart[node], p1 = rowstart[node + 1];
    float denom = 0.f;
    f32x4 acc = {0.f, 0.f, 0.f, 0.f};
    int p = p0;
    for (; p + 8 <= p1; p += 8) {
        int sidx[8];
        #pragma unroll
        for (int j = 0; j < 8; ++j) sidx[j] = esrc[p + j];
        us8 w[8];
        #pragma unroll
        for (int j = 0; j < 8; ++j)
            w[j] = *(const us8*)(qv + (size_t)sidx[j] * 512 + lane8);
        float a[8];
        #pragma unroll
        for (int j = 0; j < 8; ++j)
            a[j] = __expf(red16(dotqv(w[j], kf)) * 0.125f);
        #pragma unroll
        for (int j = 0; j < 8; ++j) {
            denom += a[j];
            for (int i = 0; i < 4; ++i) acc[i] += a[j] * bf2f(w[j][2 * i + 1]);
        }
    }
    for (; p + 4 <= p1; p += 4) {
        int sidx[4];
        #pragma unroll
        for (int j = 0; j < 4; ++j) sidx[j] = esrc[p + j];
        us8 w[4];
        #pragma unroll
        for (int j = 0; j < 4; ++j)
            w[j] = *(const us8*)(qv + (size_t)sidx[j] * 512 + lane8);
        float a[4];
        #pragma unroll
        for (int j = 0; j < 4; ++j)
            a[j] = __expf(red16(dotqv(w[j], kf)) * 0.125f);
        #pragma unroll
        for (int j = 0; j < 4; ++j) {
            denom += a[j];
            for (int i = 0; i < 4; ++i) acc[i] += a[j] * bf2f(w[j][2 * i + 1]);
        }
    }
    for (; p < p1; ++p) {
        int s = esrc[p];
        us8 w = *(const us8*)(qv + (size_t)s * 512 + lane8);
        float a = __expf(red16(dotqv(w, kf)) * 0.125f);
        denom += a;
        for (int i = 0; i < 4; ++i) acc[i] += a * bf2f(w[2 * i + 1]);
    }
    float inv = denom > 0.f ? 1.f / denom : 0.f;
    float rst[4];
    for (int i = 0; i < 4; ++i) rst[i] = acc[i] * inv;

    // ---- gate + LN + PReLU (fused epilogue) ----
    us4 sk4 = __builtin_nontemporal_load((const us4*)(skipb + (size_t)node * 256 + lane4));
    float sk[4];
    for (int i = 0; i < 4; ++i) sk[i] = bf2f(sk4[i]);
    f32x4 ga = *(const f32x4*)(wga + lane4);
    f32x4 gb = *(const f32x4*)(wgb + lane4);
    float g = 0.f;
    for (int i = 0; i < 4; ++i) g += sk[i] * ga[i] + rst[i] * gb[i];
    for (int off = 1; off < 64; off <<= 1) g += __shfl_xor(g, off, 64);
    float gate = 1.f / (1.f + __expf(-(g + bgp[0])));
    float r[4], s1v = 0.f, s2v = 0.f;
    for (int i = 0; i < 4; ++i) {
        r[i] = gate * sk[i] + (1.f - gate) * rst[i];
        s1v += r[i]; s2v += r[i] * r[i];
    }
    for (int off = 1; off < 64; off <<= 1) {
        s1v += __shfl_xor(s1v, off, 64);
        s2v += __shfl_xor(s2v, off, 64);
    }
    float mean = s1v * (1.f / 256.f);
    float var = s2v * (1.f / 256.f) - mean * mean;
    float rsig = rsqrtf(var + 1e-5f);
    f32x4 sc4 = *(const f32x4*)(lns + lane4);
    f32x4 bi4 = *(const f32x4*)(lnb + lane4);
    float alpha = alphap[0];
    f32x4 y;
    for (int i = 0; i < 4; ++i) {
        float v = (r[i] - mean) * rsig * sc4[i] + bi4[i];
        y[i] = v > 0.f ? v : alpha * v;
    }
    __builtin_nontemporal_store(y, (f32x4*)(out + (size_t)node * 256 + lane4));
}

extern "C" void kernel_launch(void* const* d_in, const int* in_sizes, int n_in,
                              void* d_out, int out_size, void* d_ws, size_t ws_size,
                              hipStream_t stream)
{
    const float* feat = (const float*)d_in[0];
    const int* src = (const int*)d_in[1];
    const int* dst = (const int*)d_in[2];
    const float* Wq = (const float*)d_in[3];
    const float* bq = (const float*)d_in[4];
    const float* Wk = (const float*)d_in[5];
    const float* bk = (const float*)d_in[6];
    const float* Wv = (const float*)d_in[7];
    const float* bv = (const float*)d_in[8];
    const float* Ws = (const float*)d_in[9];
    const float* bs = (const float*)d_in[10];
    const float* Wg = (const float*)d_in[11];
    const float* bg = (const float*)d_in[12];
    const float* lns = (const float*)d_in[13];
    const float* lnb = (const float*)d_in[14];
    const float* alpha = (const float*)d_in[15];
    int N = in_sizes[0] / 256;
    int E = in_sizes[1];

    char* w = (char*)d_ws;
    size_t off = 0;
    auto alloc = [&](size_t b) { char* p = w + off; off += (b + 255) & ~(size_t)255; return p; };
    unsigned short* Wt    = (unsigned short*)alloc((size_t)1024 * 256 * 2);
    float* ball = (float*)alloc(1024 * 4);
    float* wga  = (float*)alloc(256 * 4);
    float* wgb  = (float*)alloc(256 * 4);
    unsigned short* qv    = (unsigned short*)alloc((size_t)N * 512 * 2);
    unsigned short* kb    = (unsigned short*)alloc((size_t)N * 256 * 2);
    unsigned short* skipb = (unsigned short*)alloc((size_t)N * 256 * 2);
    int* cnt = (int*)alloc((size_t)N * 4);
    int* rowstart = (int*)alloc(((size_t)N + 1) * 4);
    int* bsum = (int*)alloc(256 * 4);
    int* esrc = (int*)alloc((size_t)E * 4);
    float* outf = (float*)d_out;

    hipMemsetAsync(cnt, 0, (size_t)N * 4, stream);

    k_conv_w<<<256, 256, 0, stream>>>(Wq, Wk, Wv, Ws, bq, bk, bv, bs, Wg, Wt, ball, wga, wgb);

    int MB = (N + BM - 1) / BM;                    // 391
    int gridg = ((MB + 7) / 8) * 64;               // 3136, guarded in-kernel
    k_gemm<<<gridg, 256, 0, stream>>>(feat, Wt, ball, qv, kb, skipb, N, MB);

    int eb = (E + 255) / 256;
    k_count<<<eb, 256, 0, stream>>>(dst, cnt, E);
    int nb = (N + 255) / 256;
    k_scan1<<<nb, 256, 0, stream>>>(cnt, rowstart, bsum, N);
    k_scan2<<<1, 256, 0, stream>>>(bsum, nb);
    k_scan3<<<nb, 256, 0, stream>>>(cnt, rowstart, bsum, N, E);
    hipMemsetAsync(cnt, 0, (size_t)N * 4, stream);
    k_scatter<<<eb, 256, 0, stream>>>(src, dst, rowstart, cnt, esrc, E);

    k_attn<<<(N + 3) / 4, 256, 0, stream>>>(qv, kb, skipb, rowstart, esrc,
                                            wga, wgb, bg, lns, lnb, alpha, outf, N);
}

// Round 10
// 304.049 us; speedup vs baseline: 2.3033x; 2.3033x over previous
//
#include <hip/hip_runtime.h>
#include <hip/hip_bf16.h>

typedef __attribute__((ext_vector_type(4))) float f32x4;
typedef __attribute__((ext_vector_type(8))) short bf16x8;
typedef __attribute__((ext_vector_type(8))) unsigned short us8;
typedef __attribute__((ext_vector_type(4))) unsigned short us4;

__device__ __forceinline__ float bf2f(unsigned short u) {
    union { unsigned int i; float f; } x; x.i = ((unsigned int)u) << 16; return x.f;
}
__device__ __forceinline__ unsigned short f2bf(float f) {
    union { float f; unsigned int i; } x; x.f = f;
    unsigned int i = x.i;
    return (unsigned short)((i + 0x7FFFu + ((i >> 16) & 1u)) >> 16);
}

// ---------------- build Wt[1024][256] bf16 (transposed), biases, gate vecs ----------------
__global__ void k_conv_w(const float* __restrict__ Wq, const float* __restrict__ Wk,
                         const float* __restrict__ Wv, const float* __restrict__ Ws,
                         const float* __restrict__ bq, const float* __restrict__ bk,
                         const float* __restrict__ bv, const float* __restrict__ bs,
                         const float* __restrict__ Wg,
                         unsigned short* __restrict__ Wt, float* __restrict__ ball,
                         float* __restrict__ wga, float* __restrict__ wgb)
{
    int gid = blockIdx.x * 256 + threadIdx.x;  // 65536 threads
    int k = gid >> 8, colq = gid & 255;
    int col0 = colq * 4;
    const float* Wsel[4] = {Wq, Wk, Wv, Ws};
    const float* W = Wsel[col0 >> 8];
    int c0 = col0 & 255;
    f32x4 w = *(const f32x4*)(W + k * 256 + c0);
    for (int j = 0; j < 4; ++j)
        Wt[(size_t)(col0 + j) * 256 + k] = f2bf(w[j]);
    if (gid < 1024) {
        const float* bsel[4] = {bq, bk, bv, bs};
        ball[gid] = bsel[gid >> 8][gid & 255];
    } else if (gid < 1280) {
        int i = gid - 1024;
        wga[i] = Wg[i] + Wg[512 + i];          // coeff on skip
    } else if (gid < 1536) {
        int i = gid - 1280;
        wgb[i] = Wg[256 + i] - Wg[512 + i];    // coeff on rst
    }
}

// ---------------- fused QKV+skip GEMM: feat fp32 [M,256] x Wt [256,1024] ----------------
// Epilogue layout is the R8-PROVEN one: qkvb[row][768] bf16 contiguous + skipf fp32.
// (3-buffer / interleaved bf16 epilogues caused 16x HBM write amplification - R4/R9.)
#define BM 128
#define BN 128
#define BK 64
#define SST 72   // LDS row stride in bf16: 144B = 16B-aligned, bank-step 4 -> conflict-free

__global__ __launch_bounds__(256) void k_gemm(
    const float* __restrict__ A, const unsigned short* __restrict__ Bt,
    const float* __restrict__ bias, unsigned short* __restrict__ qkvb,
    float* __restrict__ skipf, int M, int MB)
{
    __shared__ unsigned short a_sm[BM * SST];
    __shared__ unsigned short b_sm[BN * SST];
    int id = blockIdx.x;
    int rr = id & 7, bn = (id >> 3) & 7, bm = (id >> 6) * 8 + rr;  // XCD-cohort swizzle
    if (bm >= MB) return;
    int t = threadIdx.x;
    int lane = t & 63, wid = t >> 6;
    int wr = wid >> 1, wc = wid & 1;
    int l15 = lane & 15, l4 = lane >> 4;
    f32x4 acc[4][4] = {};
    for (int k0 = 0; k0 < 256; k0 += BK) {
        for (int it = 0; it < 4; ++it) {
            int c = it * 256 + t;
            int row = c >> 3;
            int ko = (c & 7) * 8;
            int grow = bm * BM + row;
            if (grow >= M) grow = M - 1;
            // A: fp32 load + convert (fused feat convert)
            const f32x4* pa = (const f32x4*)(A + (size_t)grow * 256 + k0 + ko);
            f32x4 x = pa[0], y = pa[1];
            us8 o;
            o[0] = f2bf(x[0]); o[1] = f2bf(x[1]); o[2] = f2bf(x[2]); o[3] = f2bf(x[3]);
            o[4] = f2bf(y[0]); o[5] = f2bf(y[1]); o[6] = f2bf(y[2]); o[7] = f2bf(y[3]);
            *(us8*)(a_sm + row * SST + ko) = o;
            int gcol = bn * BN + row;
            us8 vb = *(const us8*)(Bt + (size_t)gcol * 256 + k0 + ko);
            *(us8*)(b_sm + row * SST + ko) = vb;
        }
        __syncthreads();
        for (int kk = 0; kk < BK; kk += 32) {
            bf16x8 af[4], bf[4];
            for (int mi = 0; mi < 4; ++mi)
                af[mi] = *(const bf16x8*)(a_sm + (wr * 64 + mi * 16 + l15) * SST + kk + l4 * 8);
            for (int ni = 0; ni < 4; ++ni)
                bf[ni] = *(const bf16x8*)(b_sm + (wc * 64 + ni * 16 + l15) * SST + kk + l4 * 8);
            for (int mi = 0; mi < 4; ++mi)
                for (int ni = 0; ni < 4; ++ni)
                    acc[mi][ni] = __builtin_amdgcn_mfma_f32_16x16x32_bf16(af[mi], bf[ni], acc[mi][ni], 0, 0, 0);
        }
        __syncthreads();
    }
    int colb = bn * BN + wc * 64 + l15;
    for (int mi = 0; mi < 4; ++mi) {
        int rowb = bm * BM + wr * 64 + mi * 16 + l4 * 4;
        for (int ni = 0; ni < 4; ++ni) {
            int col = colb + ni * 16;
            float bv = bias[col];
            for (int r = 0; r < 4; ++r) {
                int row = rowb + r;
                if (row < M) {
                    float v = acc[mi][ni][r] + bv;
                    if (col < 768) qkvb[(size_t)row * 768 + col] = f2bf(v);
                    else skipf[(size_t)row * 256 + (col - 768)] = v;
                }
            }
        }
    }
}

// ---------------- CSR build ----------------
__global__ void k_count(const int* __restrict__ dst, int* __restrict__ cnt, int e) {
    int t = blockIdx.x * 256 + threadIdx.x;
    if (t < e) atomicAdd(&cnt[dst[t]], 1);
}
__global__ void k_scan1(const int* __restrict__ cnt, int* __restrict__ inc, int* __restrict__ bsum, int n) {
    int t = threadIdx.x;
    int i = blockIdx.x * 256 + t;
    int lane = t & 63, w = t >> 6;
    int v = (i < n) ? cnt[i] : 0;
    int s = v;
    for (int off = 1; off < 64; off <<= 1) {
        int u = __shfl_up(s, off, 64);
        if (lane >= off) s += u;
    }
    __shared__ int wt[4];
    if (lane == 63) wt[w] = s;
    __syncthreads();
    for (int j = 0; j < w; ++j) s += wt[j];
    if (i < n) inc[i] = s;
    if (t == 255) bsum[blockIdx.x] = s;
}
__global__ void k_scan2(int* __restrict__ bsum, int nb) {
    int t = threadIdx.x;
    int lane = t & 63, w = t >> 6;
    int v = (t < nb) ? bsum[t] : 0;
    int s = v;
    for (int off = 1; off < 64; off <<= 1) {
        int u = __shfl_up(s, off, 64);
        if (lane >= off) s += u;
    }
    __shared__ int wt[4];
    if (lane == 63) wt[w] = s;
    __syncthreads();
    for (int j = 0; j < w; ++j) s += wt[j];
    if (t < nb) bsum[t] = s - v;
}
__global__ void k_scan3(const int* __restrict__ cnt, int* __restrict__ rowstart, const int* __restrict__ bsum, int n, int e) {
    int i = blockIdx.x * 256 + threadIdx.x;
    if (i < n) rowstart[i] = bsum[blockIdx.x] + rowstart[i] - cnt[i];
    if (i == 0) rowstart[n] = e;
}
__global__ void k_scatter(const int* __restrict__ src, const int* __restrict__ dst,
                          const int* __restrict__ rowstart, int* __restrict__ cur,
                          int* __restrict__ esrc, int e) {
    int t = blockIdx.x * 256 + threadIdx.x;
    if (t < e) {
        int d = dst[t];
        int pos = rowstart[d] + atomicAdd(&cur[d], 1);
        esrc[pos] = src[t];
    }
}

// ---------------- fused attn + gate + LN + PReLU: one wave per dst node ----------------
__device__ __forceinline__ float dot4k(us4 q, const float* kf) {
    return bf2f(q[0]) * kf[0] + bf2f(q[1]) * kf[1] + bf2f(q[2]) * kf[2] + bf2f(q[3]) * kf[3];
}
__device__ __forceinline__ float red16(float sc) {
    sc += __shfl_xor(sc, 1, 16);
    sc += __shfl_xor(sc, 2, 16);
    sc += __shfl_xor(sc, 4, 16);
    sc += __shfl_xor(sc, 8, 16);
    return sc;
}

__global__ void k_attn(const unsigned short* __restrict__ qkvb,
                       const float* __restrict__ skipf,
                       const int* __restrict__ rowstart, const int* __restrict__ esrc,
                       const float* __restrict__ wga, const float* __restrict__ wgb,
                       const float* __restrict__ bgp, const float* __restrict__ lns,
                       const float* __restrict__ lnb, const float* __restrict__ alphap,
                       float* __restrict__ out, int n)
{
    int node = blockIdx.x * 4 + (threadIdx.x >> 6);
    if (node >= n) return;
    int lane = threadIdx.x & 63;
    int lane4 = lane * 4;
    // lane l covers feature cols 4l..4l+3; head = l>>4
    us4 k4 = __builtin_nontemporal_load((const us4*)(qkvb + (size_t)node * 768 + 256 + lane4));
    float kf[4];
    for (int i = 0; i < 4; ++i) kf[i] = bf2f(k4[i]);
    int p0 = rowstart[node], p1 = rowstart[node + 1];
    float denom = 0.f;
    f32x4 acc = {0.f, 0.f, 0.f, 0.f};
    int p = p0;
    for (; p + 8 <= p1; p += 8) {
        int sidx[8];
        #pragma unroll
        for (int j = 0; j < 8; ++j) sidx[j] = esrc[p + j];
        us4 q[8], v[8];
        #pragma unroll
        for (int j = 0; j < 8; ++j) {
            const unsigned short* r = qkvb + (size_t)sidx[j] * 768 + lane4;
            q[j] = *(const us4*)(r);
            v[j] = *(const us4*)(r + 512);
        }
        float a[8];
        #pragma unroll
        for (int j = 0; j < 8; ++j)
            a[j] = __expf(red16(dot4k(q[j], kf)) * 0.125f);
        #pragma unroll
        for (int j = 0; j < 8; ++j) {
            denom += a[j];
            for (int i = 0; i < 4; ++i) acc[i] += a[j] * bf2f(v[j][i]);
        }
    }
    for (; p + 4 <= p1; p += 4) {
        int sidx[4];
        #pragma unroll
        for (int j = 0; j < 4; ++j) sidx[j] = esrc[p + j];
        us4 q[4], v[4];
        #pragma unroll
        for (int j = 0; j < 4; ++j) {
            const unsigned short* r = qkvb + (size_t)sidx[j] * 768 + lane4;
            q[j] = *(const us4*)(r);
            v[j] = *(const us4*)(r + 512);
        }
        float a[4];
        #pragma unroll
        for (int j = 0; j < 4; ++j)
            a[j] = __expf(red16(dot4k(q[j], kf)) * 0.125f);
        #pragma unroll
        for (int j = 0; j < 4; ++j) {
            denom += a[j];
            for (int i = 0; i < 4; ++i) acc[i] += a[j] * bf2f(v[j][i]);
        }
    }
    for (; p < p1; ++p) {
        int s = esrc[p];
        const unsigned short* r = qkvb + (size_t)s * 768 + lane4;
        us4 q4 = *(const us4*)(r);
        us4 v4 = *(const us4*)(r + 512);
        float sc = red16(dot4k(q4, kf));
        float a = __expf(sc * 0.125f);
        denom += a;
        for (int i = 0; i < 4; ++i) acc[i] += a * bf2f(v4[i]);
    }
    float inv = denom > 0.f ? 1.f / denom : 0.f;
    float rst[4];
    for (int i = 0; i < 4; ++i) rst[i] = acc[i] * inv;

    // ---- gate + LN + PReLU (fused epilogue) ----
    f32x4 sk = __builtin_nontemporal_load((const f32x4*)(skipf + (size_t)node * 256 + lane4));
    f32x4 ga = *(const f32x4*)(wga + lane4);
    f32x4 gb = *(const f32x4*)(wgb + lane4);
    float g = 0.f;
    for (int i = 0; i < 4; ++i) g += sk[i] * ga[i] + rst[i] * gb[i];
    for (int off = 1; off < 64; off <<= 1) g += __shfl_xor(g, off, 64);
    float gate = 1.f / (1.f + __expf(-(g + bgp[0])));
    float r[4], s1v = 0.f, s2v = 0.f;
    for (int i = 0; i < 4; ++i) {
        r[i] = gate * sk[i] + (1.f - gate) * rst[i];
        s1v += r[i]; s2v += r[i] * r[i];
    }
    for (int off = 1; off < 64; off <<= 1) {
        s1v += __shfl_xor(s1v, off, 64);
        s2v += __shfl_xor(s2v, off, 64);
    }
    float mean = s1v * (1.f / 256.f);
    float var = s2v * (1.f / 256.f) - mean * mean;
    float rsig = rsqrtf(var + 1e-5f);
    f32x4 sc4 = *(const f32x4*)(lns + lane4);
    f32x4 bi4 = *(const f32x4*)(lnb + lane4);
    float alpha = alphap[0];
    f32x4 y;
    for (int i = 0; i < 4; ++i) {
        float v = (r[i] - mean) * rsig * sc4[i] + bi4[i];
        y[i] = v > 0.f ? v : alpha * v;
    }
    __builtin_nontemporal_store(y, (f32x4*)(out + (size_t)node * 256 + lane4));
}

extern "C" void kernel_launch(void* const* d_in, const int* in_sizes, int n_in,
                              void* d_out, int out_size, void* d_ws, size_t ws_size,
                              hipStream_t stream)
{
    const float* feat = (const float*)d_in[0];
    const int* src = (const int*)d_in[1];
    const int* dst = (const int*)d_in[2];
    const float* Wq = (const float*)d_in[3];
    const float* bq = (const float*)d_in[4];
    const float* Wk = (const float*)d_in[5];
    const float* bk = (const float*)d_in[6];
    const float* Wv = (const float*)d_in[7];
    const float* bv = (const float*)d_in[8];
    const float* Ws = (const float*)d_in[9];
    const float* bs = (const float*)d_in[10];
    const float* Wg = (const float*)d_in[11];
    const float* bg = (const float*)d_in[12];
    const float* lns = (const float*)d_in[13];
    const float* lnb = (const float*)d_in[14];
    const float* alpha = (const float*)d_in[15];
    int N = in_sizes[0] / 256;
    int E = in_sizes[1];

    char* w = (char*)d_ws;
    size_t off = 0;
    auto alloc = [&](size_t b) { char* p = w + off; off += (b + 255) & ~(size_t)255; return p; };
    unsigned short* Wt    = (unsigned short*)alloc((size_t)1024 * 256 * 2);
    float* ball = (float*)alloc(1024 * 4);
    float* wga  = (float*)alloc(256 * 4);
    float* wgb  = (float*)alloc(256 * 4);
    unsigned short* qkvb = (unsigned short*)alloc((size_t)N * 768 * 2);
    float* skipf = (float*)alloc((size_t)N * 256 * 4);
    int* cnt = (int*)alloc((size_t)N * 4);
    int* rowstart = (int*)alloc(((size_t)N + 1) * 4);
    int* bsum = (int*)alloc(256 * 4);
    int* esrc = (int*)alloc((size_t)E * 4);
    float* outf = (float*)d_out;

    hipMemsetAsync(cnt, 0, (size_t)N * 4, stream);

    k_conv_w<<<256, 256, 0, stream>>>(Wq, Wk, Wv, Ws, bq, bk, bv, bs, Wg, Wt, ball, wga, wgb);

    int MB = (N + BM - 1) / BM;                    // 391
    int gridg = ((MB + 7) / 8) * 64;               // 3136, guarded in-kernel
    k_gemm<<<gridg, 256, 0, stream>>>(feat, Wt, ball, qkvb, skipf, N, MB);

    int eb = (E + 255) / 256;
    k_count<<<eb, 256, 0, stream>>>(dst, cnt, E);
    int nb = (N + 255) / 256;
    k_scan1<<<nb, 256, 0, stream>>>(cnt, rowstart, bsum, N);
    k_scan2<<<1, 256, 0, stream>>>(bsum, nb);
    k_scan3<<<nb, 256, 0, stream>>>(cnt, rowstart, bsum, N, E);
    hipMemsetAsync(cnt, 0, (size_t)N * 4, stream);
    k_scatter<<<eb, 256, 0, stream>>>(src, dst, rowstart, cnt, esrc, E);

    k_attn<<<(N + 3) / 4, 256, 0, stream>>>(qkvb, skipf, rowstart, esrc,
                                            wga, wgb, bg, lns, lnb, alpha, outf, N);
}